// Round 1
// baseline (1064.707 us; speedup 1.0000x reference)
//
#include <hip/hip_runtime.h>
#include <math.h>

// ---------------------------------------------------------------- constants
#define BB 8
#define TT 2048
#define DV_ 1024
#define DA_ 128
#define D1_ 512
#define D2_ 128
#define DH_ 257
#define DHP 264            // padded (zeros) so K-loops are uniform, 8-aligned
#define DG_ 128
#define MTOT (BB*TT)       // 16384 rows
#define NPX ((size_t)MTOT*DHP)

#define NEGS 0.01f
#define INV_E 0.36787944117144233f

// workspace layout (float offsets)
//  o_px  : px  [16384][264]
//  o_acc : adj corrections -> becomes Y1 in place
//  o_A   : C1 [16384][512]  ; later Y2 [16384][264], x1 [16384][128], x2f [16384][128]
//  o_C2  : C2 [16384][128]
//  o_S   : per-batch valid column sum [8][264]
//  o_den : softmax denominators [16384]
//  o_g1/o_g2 : zero-padded gw1/gw2 [264][128]
static const size_t o_px  = 0;
static const size_t o_acc = NPX;                       // 4,325,376
static const size_t o_A   = 2*NPX;                     // 8,650,752
static const size_t o_C2  = o_A + NPX + 2ull*MTOT*128; // 17,170,432
static const size_t o_S   = o_C2 + (size_t)MTOT*128;   // 19,267,584
static const size_t o_den = o_S + BB*DHP;              // 19,269,696
static const size_t o_g1  = o_den + MTOT;              // 19,286,080
static const size_t o_g2  = o_g1 + DHP*DG_;            // 19,319,872

// ---------------------------------------------------------------- utilities
__global__ void k_zero(float* __restrict__ p, size_t n) {
    size_t i = (size_t)blockIdx.x * 256 + threadIdx.x;
    size_t stride = (size_t)gridDim.x * 256;
    for (; i < n; i += stride) p[i] = 0.f;
}

__global__ void k_den_init(float* __restrict__ den, const int* __restrict__ seq) {
    int r = blockIdx.x * 256 + threadIdx.x;   // 16384 total
    den[r] = (float)seq[r >> 11];
}

__global__ void k_padgw(const float* __restrict__ g, float* __restrict__ gp) {
    int i = blockIdx.x * 256 + threadIdx.x;   // DHP*DG total
    if (i < DHP * DG_) gp[i] = (i < DH_ * DG_) ? g[i] : 0.f;
}

// ------------------------------------------------- GEMM: C = leaky(A*W^T + b)
// A [M x K] row stride lda ; W [N x K] row-major ; C [M x N]
// tiles 64x64, BK=16, 256 threads, 4x4 per thread. All dims divide evenly.
__global__ __launch_bounds__(256) void gemm_nt_leaky(
    const float* __restrict__ A, int lda,
    const float* __restrict__ W, const float* __restrict__ bias,
    float* __restrict__ C, int N, int K)
{
    __shared__ float As[16][68];
    __shared__ float Ws[16][68];
    const int row0 = blockIdx.y * 64, col0 = blockIdx.x * 64;
    const int tid = threadIdx.x;
    const int tx = tid & 15, ty = tid >> 4;
    const int lr = tid >> 2, lc = (tid & 3) * 4;
    float acc[4][4] = {};
    for (int k0 = 0; k0 < K; k0 += 16) {
        float4 av = *(const float4*)(A + (size_t)(row0 + lr) * lda + k0 + lc);
        float4 wv = *(const float4*)(W + (size_t)(col0 + lr) * K + k0 + lc);
        __syncthreads();
        As[lc+0][lr]=av.x; As[lc+1][lr]=av.y; As[lc+2][lr]=av.z; As[lc+3][lr]=av.w;
        Ws[lc+0][lr]=wv.x; Ws[lc+1][lr]=wv.y; Ws[lc+2][lr]=wv.z; Ws[lc+3][lr]=wv.w;
        __syncthreads();
#pragma unroll
        for (int k = 0; k < 16; ++k) {
            float4 a = *(const float4*)&As[k][ty*4];
            float4 w = *(const float4*)&Ws[k][tx*4];
            acc[0][0]+=a.x*w.x; acc[0][1]+=a.x*w.y; acc[0][2]+=a.x*w.z; acc[0][3]+=a.x*w.w;
            acc[1][0]+=a.y*w.x; acc[1][1]+=a.y*w.y; acc[1][2]+=a.y*w.z; acc[1][3]+=a.y*w.w;
            acc[2][0]+=a.z*w.x; acc[2][1]+=a.z*w.y; acc[2][2]+=a.z*w.z; acc[2][3]+=a.z*w.w;
            acc[3][0]+=a.w*w.x; acc[3][1]+=a.w*w.y; acc[3][2]+=a.w*w.z; acc[3][3]+=a.w*w.w;
        }
    }
#pragma unroll
    for (int ii = 0; ii < 4; ++ii)
#pragma unroll
        for (int jj = 0; jj < 4; ++jj) {
            int m = row0 + ty*4 + ii, n = col0 + tx*4 + jj;
            float v = acc[ii][jj] + bias[n];
            C[(size_t)m * N + n] = (v >= 0.f) ? v : NEGS * v;
        }
}

// ------------------------------------------------- GEMM: C = leaky(A*G)  (NN)
// A [M x 264] row stride DHP ; G [264 x 128] row-major ; C [M x 128]
__global__ __launch_bounds__(256) void gemm_nn_leaky(
    const float* __restrict__ A, const float* __restrict__ G,
    float* __restrict__ C)
{
    __shared__ float As[8][68];
    __shared__ float Gs[8][68];
    const int row0 = blockIdx.y * 64, col0 = blockIdx.x * 64;
    const int tid = threadIdx.x;
    const int tx = tid & 15, ty = tid >> 4;
    const int lr = tid >> 2, lc = (tid & 3) * 2;
    const int gk = tid >> 6, gc = tid & 63;
    float acc[4][4] = {};
    for (int k0 = 0; k0 < DHP; k0 += 8) {
        float2 av = *(const float2*)(A + (size_t)(row0 + lr) * DHP + k0 + lc);
        float g0 = G[(size_t)(k0 + gk) * DG_ + col0 + gc];
        float g1 = G[(size_t)(k0 + gk + 4) * DG_ + col0 + gc];
        __syncthreads();
        As[lc+0][lr] = av.x; As[lc+1][lr] = av.y;
        Gs[gk][gc] = g0; Gs[gk+4][gc] = g1;
        __syncthreads();
#pragma unroll
        for (int k = 0; k < 8; ++k) {
            float4 a = *(const float4*)&As[k][ty*4];
            float4 g = *(const float4*)&Gs[k][tx*4];
            acc[0][0]+=a.x*g.x; acc[0][1]+=a.x*g.y; acc[0][2]+=a.x*g.z; acc[0][3]+=a.x*g.w;
            acc[1][0]+=a.y*g.x; acc[1][1]+=a.y*g.y; acc[1][2]+=a.y*g.z; acc[1][3]+=a.y*g.w;
            acc[2][0]+=a.z*g.x; acc[2][1]+=a.z*g.y; acc[2][2]+=a.z*g.z; acc[2][3]+=a.z*g.w;
            acc[3][0]+=a.w*g.x; acc[3][1]+=a.w*g.y; acc[3][2]+=a.w*g.z; acc[3][3]+=a.w*g.w;
        }
    }
#pragma unroll
    for (int ii = 0; ii < 4; ++ii)
#pragma unroll
        for (int jj = 0; jj < 4; ++jj) {
            int m = row0 + ty*4 + ii, n = col0 + tx*4 + jj;
            float v = acc[ii][jj];
            C[(size_t)m * DG_ + n] = (v >= 0.f) ? v : NEGS * v;
        }
}

// ------------------------------------------------- expmap0 (build px)
// one block per row; 256 threads = 256 spatial dims
__global__ __launch_bounds__(256) void k_proj(
    const float* __restrict__ C2, const float* __restrict__ inputs,
    float* __restrict__ px)
{
    const int r = blockIdx.x;
    const int tid = threadIdx.x;
    float v = (tid < 128) ? C2[(size_t)r * 128 + tid]
                          : inputs[(size_t)r * 1152 + 1024 + (tid - 128)];
    float sq = v * v;
#pragma unroll
    for (int o = 32; o > 0; o >>= 1) sq += __shfl_down(sq, o, 64);
    __shared__ float wred[4];
    __shared__ float cs[2];
    if ((tid & 63) == 0) wred[tid >> 6] = sq;
    __syncthreads();
    if (tid == 0) {
        float n2 = fmaxf(wred[0] + wred[1] + wred[2] + wred[3], 1e-12f);
        float n = sqrtf(n2);
        cs[0] = coshf(n);
        cs[1] = sinhf(n) / n;
    }
    __syncthreads();
    float s = cs[1];
    px[(size_t)r * DHP + 1 + tid] = s * v;
    if (tid == 0) px[(size_t)r * DHP] = cs[0];
    if (tid < DHP - DH_) px[(size_t)r * DHP + DH_ + tid] = 0.f;  // 7 pad zeros
}

// ------------------------------------------------- per-batch valid column sum
__global__ __launch_bounds__(256) void k_ssum(
    const float* __restrict__ px, const int* __restrict__ seq,
    float* __restrict__ S)
{
    const int b = blockIdx.x, chunk = blockIdx.y, tid = threadIdx.x;
    const int nb = seq[b];
    const int j0 = chunk * 128;
    const int j1 = (j0 + 128 < nb) ? j0 + 128 : nb;
    float a0 = 0.f, a1 = 0.f;
    const bool hasB = (tid < DHP - 256);
    for (int j = j0; j < j1; ++j) {
        const float* row = px + ((size_t)(b * TT + j)) * DHP;
        a0 += row[tid];
        if (hasB) a1 += row[256 + tid];
    }
    if (j1 > j0) {
        atomicAdd(&S[b * DHP + tid], a0);
        if (hasB) atomicAdd(&S[b * DHP + 256 + tid], a1);
    }
}

// ------------------------------------------------- xy GEMM + sparse corrections
// xy[i][j] = 2*c_i*c_j - dot264(px_i, px_j); diag forced to exact 1.0.
// If x2=exp(-d(xy)) > 0.8 (and i,j valid): den_i += e^x2-1 ; acc_i += (e^x2-1)*px_j
__global__ __launch_bounds__(256) void k_xy(
    const float* __restrict__ px, const int* __restrict__ seq,
    float* __restrict__ den, float* __restrict__ acc)
{
    const int b = blockIdx.z;
    const int nb = seq[b];
    const int row0 = blockIdx.y * 64, col0 = blockIdx.x * 64;
    if (row0 >= nb || col0 >= nb) return;   // rows >= nb produce Y1=0; cols >= nb masked
    const float* base = px + (size_t)b * TT * DHP;
    __shared__ float As[8][68];
    __shared__ float Bs[8][68];
    const int tid = threadIdx.x;
    const int tx = tid & 15, ty = tid >> 4;
    const int lr = tid >> 2, lc = (tid & 3) * 2;
    float dot[4][4] = {};
    for (int k0 = 0; k0 < DHP; k0 += 8) {
        float2 av = *(const float2*)(base + (size_t)(row0 + lr) * DHP + k0 + lc);
        float2 bv = *(const float2*)(base + (size_t)(col0 + lr) * DHP + k0 + lc);
        __syncthreads();
        As[lc+0][lr] = av.x; As[lc+1][lr] = av.y;
        Bs[lc+0][lr] = bv.x; Bs[lc+1][lr] = bv.y;
        __syncthreads();
#pragma unroll
        for (int k = 0; k < 8; ++k) {
            float4 a = *(const float4*)&As[k][ty*4];
            float4 w = *(const float4*)&Bs[k][tx*4];
            dot[0][0]+=a.x*w.x; dot[0][1]+=a.x*w.y; dot[0][2]+=a.x*w.z; dot[0][3]+=a.x*w.w;
            dot[1][0]+=a.y*w.x; dot[1][1]+=a.y*w.y; dot[1][2]+=a.y*w.z; dot[1][3]+=a.y*w.w;
            dot[2][0]+=a.z*w.x; dot[2][1]+=a.z*w.y; dot[2][2]+=a.z*w.z; dot[2][3]+=a.z*w.w;
            dot[3][0]+=a.w*w.x; dot[3][1]+=a.w*w.y; dot[3][2]+=a.w*w.z; dot[3][3]+=a.w*w.w;
        }
    }
    float ci[4], cj[4];
#pragma unroll
    for (int t = 0; t < 4; ++t) {
        ci[t] = base[(size_t)(row0 + ty*4 + t) * DHP];
        cj[t] = base[(size_t)(col0 + tx*4 + t) * DHP];
    }
#pragma unroll
    for (int ii = 0; ii < 4; ++ii)
#pragma unroll
        for (int jj = 0; jj < 4; ++jj) {
            int i = row0 + ty*4 + ii, j = col0 + tx*4 + jj;
            float xyv = 2.f * ci[ii] * cj[jj] - dot[ii][jj];
            if (i == j) xyv = 1.0f;   // exact Lorentz norm; fp32 cancellation garbage otherwise
            if (i < nb && j < nb) {
                float xym = fmaxf(xyv, 1.0f);
                // xym >= 1.026 => d >= 0.2266 => x2 <= 0.798 < 0.8: no correction
                if (xym < 1.026f) {
                    float dd = logf(xym + sqrtf(xym * xym - 1.0f + 1e-7f));
                    dd = fminf(fmaxf(dd, 1e-6f), 200.0f);
                    float x2v = expf(-dd);
                    if (x2v > 0.8f) {
                        float w = expf(x2v) - 1.0f;
                        atomicAdd(&den[b * TT + i], w);
                        const float* pr = base + (size_t)j * DHP;
                        float* ar = acc + ((size_t)(b * TT + i)) * DHP;
                        for (int d = 0; d < DHP; ++d) atomicAdd(&ar[d], w * pr[d]);
                    }
                }
            }
        }
}

// ------------------------------------------------- Y1 = (S + corr)/den (in place)
__global__ void k_y1(float* __restrict__ acc, const float* __restrict__ S,
                     const float* __restrict__ den, const int* __restrict__ seq)
{
    size_t idx = (size_t)blockIdx.x * 256 + threadIdx.x;
    if (idx >= NPX) return;
    int r = (int)(idx / DHP), d = (int)(idx % DHP);
    int b = r >> 11, i = r & (TT - 1);
    float out = 0.f;
    if (i < seq[b]) out = (S[b * DHP + d] + acc[idx]) / den[r];
    acc[idx] = out;
}

// ------------------------------------------------- banded disadj @ px
// y_i[d] = sum_{|i-j|<=~128} exp(-|i-j|/e) * px_j[d]; weight at |Δ|=129 is 2e-21.
__global__ __launch_bounds__(256) void k_band(
    const float* __restrict__ px, float* __restrict__ Y2)
{
    const int b = blockIdx.y;
    const int i0 = blockIdx.x * 8;
    const int tid = threadIdx.x;
    __shared__ float wtab[144];
    if (tid < 144) wtab[tid] = expf(-(float)tid * INV_E);
    __syncthreads();
    const int jlo = (i0 - 128 > 0) ? i0 - 128 : 0;
    const int jhi = (i0 + 7 + 128 < TT - 1) ? i0 + 7 + 128 : TT - 1;
    const float* base = px + (size_t)b * TT * DHP;
    const bool hasB = (tid < DHP - 256);
    float accA[8] = {}, accB[8] = {};
    for (int j = jlo; j <= jhi; ++j) {
        float pa = base[(size_t)j * DHP + tid];
        float pb = hasB ? base[(size_t)j * DHP + 256 + tid] : 0.f;
#pragma unroll
        for (int ii = 0; ii < 8; ++ii) {
            int dd = i0 + ii - j; dd = (dd < 0) ? -dd : dd;
            float w = wtab[dd];
            accA[ii] += w * pa;
            accB[ii] += w * pb;
        }
    }
#pragma unroll
    for (int ii = 0; ii < 8; ++ii) {
        Y2[((size_t)(b * TT + i0 + ii)) * DHP + tid] = accA[ii];
        if (hasB) Y2[((size_t)(b * TT + i0 + ii)) * DHP + 256 + tid] = accB[ii];
    }
}

// ------------------------------------------------- frame_prob
__global__ __launch_bounds__(256) void k_frame(
    const float* __restrict__ x1, const float* __restrict__ x2f,
    const float* __restrict__ cls_w, const float* __restrict__ cls_b,
    float* __restrict__ dout)
{
    const int r = blockIdx.x * 4 + (threadIdx.x >> 6);
    const int lane = threadIdx.x & 63;
    float s = 0.f;
#pragma unroll
    for (int t = 0; t < 2; ++t) {
        int g = lane + t * 64;
        float cw1 = cls_w[g];
        if (g == 0) cw1 = -cw1;      // signs: only dim 0 negated
        s += x1[(size_t)r * DG_ + g] * cw1;
        s += x2f[(size_t)r * DG_ + g] * cls_w[DG_ + g];
    }
#pragma unroll
    for (int o = 32; o > 0; o >>= 1) s += __shfl_down(s, o, 64);
    if (lane == 0) dout[8 + r] = 2.0f + 2.0f * s + cls_b[0];
}

// ------------------------------------------------- top-k MIL (bitonic sort)
__global__ __launch_bounds__(256) void k_clas(
    const int* __restrict__ seq, float* __restrict__ dout)
{
    __shared__ float s[TT];
    const int b = blockIdx.x, tid = threadIdx.x;
    const int nb = seq[b];
    for (int t = tid; t < TT; t += 256)
        s[t] = (t < nb) ? dout[8 + b * TT + t] : -1e30f;
    __syncthreads();
    for (int k = 2; k <= TT; k <<= 1)
        for (int j = k >> 1; j > 0; j >>= 1) {
            for (int i = tid; i < TT; i += 256) {
                int ixj = i ^ j;
                if (ixj > i) {
                    float a = s[i], c = s[ixj];
                    bool descBlk = ((i & k) == 0);
                    if (descBlk ? (a < c) : (a > c)) { s[i] = c; s[ixj] = a; }
                }
            }
            __syncthreads();
        }
    const int kk = nb / 16 + 1;
    float part = 0.f;
    for (int t = tid; t < kk; t += 256) part += s[t];
#pragma unroll
    for (int o = 32; o > 0; o >>= 1) part += __shfl_down(part, o, 64);
    __shared__ float wred[4];
    if ((tid & 63) == 0) wred[tid >> 6] = part;
    __syncthreads();
    if (tid == 0) {
        float mil = (wred[0] + wred[1] + wred[2] + wred[3]) / (float)kk;
        dout[b] = 1.f / (1.f + expf(-mil));
    }
}

// ---------------------------------------------------------------- launch
extern "C" void kernel_launch(void* const* d_in, const int* in_sizes, int n_in,
                              void* d_out, int out_size, void* d_ws, size_t ws_size,
                              hipStream_t stream) {
    (void)in_sizes; (void)n_in; (void)out_size; (void)ws_size;
    const float* inputs = (const float*)d_in[0];
    const int*   seq    = (const int*)d_in[1];
    const float* w1     = (const float*)d_in[2];
    const float* b1     = (const float*)d_in[3];
    const float* w2     = (const float*)d_in[4];
    const float* b2     = (const float*)d_in[5];
    const float* gw1    = (const float*)d_in[6];
    const float* gw2    = (const float*)d_in[7];
    const float* cls_w  = (const float*)d_in[8];
    const float* cls_b  = (const float*)d_in[9];
    float* dout = (float*)d_out;
    float* ws = (float*)d_ws;

    float* px  = ws + o_px;
    float* acc = ws + o_acc;   // corrections -> Y1
    float* C1  = ws + o_A;
    float* Y2  = ws + o_A;
    float* x1  = ws + o_A + NPX;
    float* x2f = ws + o_A + NPX + (size_t)MTOT * 128;
    float* C2  = ws + o_C2;
    float* S   = ws + o_S;
    float* den = ws + o_den;
    float* g1p = ws + o_g1;
    float* g2p = ws + o_g2;

    // init (ws is re-poisoned before every launch)
    k_zero<<<4096, 256, 0, stream>>>(acc, NPX);
    k_zero<<<16, 256, 0, stream>>>(S, (size_t)BB * DHP);
    k_den_init<<<MTOT / 256, 256, 0, stream>>>(den, seq);
    k_padgw<<<(DHP * DG_ + 255) / 256, 256, 0, stream>>>(gw1, g1p);
    k_padgw<<<(DHP * DG_ + 255) / 256, 256, 0, stream>>>(gw2, g2p);

    // MLP
    gemm_nt_leaky<<<dim3(D1_ / 64, MTOT / 64), 256, 0, stream>>>(
        inputs, 1152, w1, b1, C1, D1_, DV_);
    gemm_nt_leaky<<<dim3(D2_ / 64, MTOT / 64), 256, 0, stream>>>(
        C1, D1_, w2, b2, C2, D2_, D1_);

    // expmap0
    k_proj<<<MTOT, 256, 0, stream>>>(C2, inputs, px);

    // valid column sums
    k_ssum<<<dim3(BB, TT / 128), 256, 0, stream>>>(px, seq, S);

    // Lorentz similarity + sparse softmax corrections
    k_xy<<<dim3(TT / 64, TT / 64, BB), 256, 0, stream>>>(px, seq, den, acc);

    // Y1 = (S + corr)/den, zero for invalid rows
    k_y1<<<(int)(NPX / 256), 256, 0, stream>>>(acc, S, den, seq);

    // banded disadj @ px
    k_band<<<dim3(TT / 8, BB), 256, 0, stream>>>(px, Y2);

    // graph-conv projections
    gemm_nn_leaky<<<dim3(DG_ / 64, MTOT / 64), 256, 0, stream>>>(acc, g1p, x1);
    gemm_nn_leaky<<<dim3(DG_ / 64, MTOT / 64), 256, 0, stream>>>(Y2, g2p, x2f);

    // frame_prob + MIL
    k_frame<<<MTOT / 4, 256, 0, stream>>>(x1, x2f, cls_w, cls_b, dout);
    k_clas<<<BB, 256, 0, stream>>>(seq, dout);
}